// Round 1
// baseline (2260.584 us; speedup 1.0000x reference)
//
#include <hip/hip_runtime.h>
#include <math.h>

// ---------------- problem constants (fixed by setup_inputs) ----------------
#define N_    256
#define T_    36
#define M_    50
#define P_    80
#define K_    161          // 1 + 2P
#define PADK  192          // K padded to 8*24, pad cols are zero
#define KC    24           // k-elements per lane (8 lanes per column)
#define NB    200          // blocks (<= 256 CUs, all co-resident)
#define NT    512          // threads per block -> 200*512/8 = 12800 columns
#define LAM_  0.1f
#define MAXIT 100

#define KM_     (K_*M_)        // 8050
#define TM_     (T_*M_)        // 1800
#define OUT_DIC 2060800        // N*K*M
#define OUT_REC 2066596        // + T*K

// ---- workspace float offsets ----
#define WS_LINV 0
#define WS_D    64             // 36*192 = 6912 floats
#define WS_ACC  8192           // 200 floats (per-iter global sum of dx^2)
#define WS_WN   8392           // 1 float  (sum of wn^2)
#define WS_BARC 8396           // unsigned: barrier count
#define WS_BARG 8397           // unsigned: barrier generation

// ---------------------------------------------------------------------------
// kernel 1: build dictionary (write dic output + padded D to ws) and
// Linv = 1/frob(DtD) using frob(DtD) == frob(D D^T)  (36x36 instead of 161^2)
// ---------------------------------------------------------------------------
__global__ __launch_bounds__(256) void k_dict(const float* __restrict__ rr,
                                              const float* __restrict__ th,
                                              float* __restrict__ out,
                                              float* __restrict__ ws) {
    __shared__ float Dl[T_*PADK];
    const int tid = threadIdx.x;
    for (int e = tid; e < T_*PADK; e += 256) {
        int t = e / PADK, k = e - (e / PADK) * PADK;
        float v = 0.f;
        if (k == 0) v = 1.f;
        else if (k <= P_)      { float r = rr[k-1];     float a = th[k-1]*(float)t;
                                 v = powf(r, (float)t) * cosf(a); }
        else if (k <= 2*P_)    { float r = rr[k-1-P_];  float a = th[k-1-P_]*(float)t;
                                 v = powf(r, (float)t) * sinf(a); }
        Dl[e] = v;
        ws[WS_D + e] = v;
        if (k < K_) out[OUT_DIC + t*K_ + k] = v;
    }
    __syncthreads();
    float loc = 0.f;
    for (int e = tid; e < T_*T_; e += 256) {
        int t1 = e / T_, t2 = e - (e / T_) * T_;
        float s = 0.f;
        for (int k = 0; k < K_; ++k) s = fmaf(Dl[t1*PADK+k], Dl[t2*PADK+k], s);
        loc = fmaf(s, s, loc);
    }
    #pragma unroll
    for (int mm = 1; mm < 64; mm <<= 1) loc += __shfl_xor(loc, mm);
    __shared__ float rb[4];
    if ((tid & 63) == 0) rb[tid >> 6] = loc;
    __syncthreads();
    if (tid == 0) {
        float tot = rb[0] + rb[1] + rb[2] + rb[3];
        ws[WS_LINV] = 1.0f / sqrtf(tot);
    }
}

// ---------------------------------------------------------------------------
// handmade grid barrier (generation-based; all NB blocks are co-resident)
// ---------------------------------------------------------------------------
__device__ __forceinline__ void grid_barrier(unsigned* cnt, unsigned* gen) {
    __syncthreads();
    if (threadIdx.x == 0) {
        __threadfence();
        unsigned g0 = __hip_atomic_load(gen, __ATOMIC_ACQUIRE, __HIP_MEMORY_SCOPE_AGENT);
        unsigned my = __hip_atomic_fetch_add(cnt, 1u, __ATOMIC_ACQ_REL, __HIP_MEMORY_SCOPE_AGENT);
        if (my == NB - 1u) {
            __hip_atomic_store(cnt, 0u, __ATOMIC_RELAXED, __HIP_MEMORY_SCOPE_AGENT);
            __hip_atomic_fetch_add(gen, 1u, __ATOMIC_RELEASE, __HIP_MEMORY_SCOPE_AGENT);
        } else {
            while (__hip_atomic_load(gen, __ATOMIC_ACQUIRE, __HIP_MEMORY_SCOPE_AGENT) == g0)
                __builtin_amdgcn_s_sleep(1);
        }
        __threadfence();
    }
    __syncthreads();
}

// ---------------------------------------------------------------------------
// kernel 2: persistent FISTA. Each column (n,m) is split across 8 lanes
// (kq = lane&7, 24 k's each, zero-padded). State fully in registers.
// ---------------------------------------------------------------------------
__global__ __launch_bounds__(NT, 2) void k_fista(const float* __restrict__ X,
                                                 float* __restrict__ out,
                                                 float* __restrict__ ws) {
    __shared__ __align__(16) float Dl[T_*PADK];
    __shared__ float rb[NT/64];
    __shared__ int   sniter;
    __shared__ float sbcast;

    unsigned* wsu = (unsigned*)ws;
    const int tid = threadIdx.x;

    for (int e = tid; e < T_*PADK; e += NT) Dl[e] = ws[WS_D + e];
    const float Linv = ws[WS_LINV];
    __syncthreads();

    const int lane  = tid & 63;
    const int kq    = lane & 7;
    const int gw    = (int)blockIdx.x * (NT/64) + (tid >> 6);
    const int col   = gw*8 + (lane >> 3);          // [0, 12800)
    const int n     = col / M_;
    const int m     = col - n*M_;
    const int kbase = kq * KC;                     // kq=7 -> all-zero pad region
    const float* Yc = X + n*TM_ + m;

    float x[KC], y[KC], b[KC], wl[KC], u[KC];

    // ---- b = Linv * (D^T Ycol) ----
    #pragma unroll
    for (int j = 0; j < KC; ++j) b[j] = 0.f;
    #pragma unroll 2
    for (int t = 0; t < T_; ++t) {
        float yv = Yc[t*M_];
        const float4* dp = (const float4*)(Dl + t*PADK + kbase);
        #pragma unroll
        for (int q = 0; q < KC/4; ++q) {
            float4 d = dp[q];
            b[4*q+0] = fmaf(d.x, yv, b[4*q+0]);
            b[4*q+1] = fmaf(d.y, yv, b[4*q+1]);
            b[4*q+2] = fmaf(d.z, yv, b[4*q+2]);
            b[4*q+3] = fmaf(d.w, yv, b[4*q+3]);
        }
    }
    #pragma unroll
    for (int j = 0; j < KC; ++j) b[j] *= Linv;

    // pass-1 weights: w = 1 -> wl = lam*Linv
    #pragma unroll
    for (int j = 0; j < KC; ++j) wl[j] = LAM_ * Linv;

    float tcur = 1.f;

    // one FISTA iteration; returns this thread's sum of dx^2
    auto iterate = [&]() -> float {
        #pragma unroll
        for (int j = 0; j < KC; ++j) u[j] = 0.f;
        #pragma unroll 2
        for (int t = 0; t < T_; ++t) {
            const float4* dp = (const float4*)(Dl + t*PADK + kbase);
            float4 da[KC/4];
            #pragma unroll
            for (int q = 0; q < KC/4; ++q) da[q] = dp[q];
            float z0=0.f, z1=0.f, z2=0.f, z3=0.f;
            #pragma unroll
            for (int q = 0; q < KC/4; ++q) {
                z0 = fmaf(da[q].x, y[4*q+0], z0);
                z1 = fmaf(da[q].y, y[4*q+1], z1);
                z2 = fmaf(da[q].z, y[4*q+2], z2);
                z3 = fmaf(da[q].w, y[4*q+3], z3);
            }
            float z = (z0+z1) + (z2+z3);
            z += __shfl_xor(z, 1);
            z += __shfl_xor(z, 2);
            z += __shfl_xor(z, 4);     // all 8 lanes of the column now hold z_t
            #pragma unroll
            for (int q = 0; q < KC/4; ++q) {
                u[4*q+0] = fmaf(da[q].x, z, u[4*q+0]);
                u[4*q+1] = fmaf(da[q].y, z, u[4*q+1]);
                u[4*q+2] = fmaf(da[q].z, z, u[4*q+2]);
                u[4*q+3] = fmaf(da[q].w, z, u[4*q+3]);
            }
        }
        float t0 = tcur;
        float t1 = 0.5f * (1.f + sqrtf(fmaf(4.f*t0, t0, 1.f)));
        float tt = (t0 - 1.f) / t1;
        tcur = t1;
        float ss = 0.f;
        #pragma unroll
        for (int j = 0; j < KC; ++j) {
            float Ay = fmaf(-Linv, u[j], y[j]);    // y - Linv*D^T(D y)
            float s  = Ay + b[j];
            float xn = fmaxf(0.f, s - wl[j]) + fminf(0.f, s + wl[j]);
            float d  = xn - x[j];
            ss   = fmaf(d, d, ss);
            y[j] = fmaf(tt, d, xn);
            x[j] = xn;
        }
        return ss;
    };

    auto run = [&](int nit, bool record, int accbase) {
        tcur = 1.f;
        #pragma unroll
        for (int j = 0; j < KC; ++j) { x[j] = 0.f; y[j] = 0.f; }
        for (int i = 0; i < nit; ++i) {
            float ss = iterate();
            if (record) {
                #pragma unroll
                for (int mm = 1; mm < 64; mm <<= 1) ss += __shfl_xor(ss, mm);
                if (lane == 0) rb[tid >> 6] = ss;
                __syncthreads();
                if (tid == 0) {
                    float tot = 0.f;
                    #pragma unroll
                    for (int wq = 0; wq < NT/64; ++wq) tot += rb[wq];
                    atomicAdd(ws + WS_ACC + accbase + i, tot);
                }
                __syncthreads();
            }
        }
    };

    const float THR2 = (1e-5f * (float)K_) * (1e-5f * (float)K_);  // (tol*K)^2

    #pragma unroll 1
    for (int pass = 0; pass < 2; ++pass) {
        // run 1: full 100 iters, record per-iter ||dx||^2 (fire-and-forget)
        run(MAXIT, true, pass*MAXIT);
        grid_barrier(wsu + WS_BARC, wsu + WS_BARG);

        // find c = first iter with conv; needed iters = c+1 (101 = never)
        if (tid == 0) sniter = MAXIT + 1;
        __syncthreads();
        if (tid < MAXIT) {
            float a = __hip_atomic_load(ws + WS_ACC + pass*MAXIT + tid,
                                        __ATOMIC_RELAXED, __HIP_MEMORY_SCOPE_AGENT);
            if (a < THR2) atomicMin(&sniter, tid + 1);
        }
        __syncthreads();
        int nit2 = sniter;                 // uniform across the whole grid
        if (nit2 < MAXIT) run(nit2, false, 0);   // deterministic replay to x_{c+1}

        if (pass == 0) {
            // reweight: wn = 1/(|code|+0.01); w = wn/||wn||*K; wl = w*lam*Linv
            float loc = 0.f;
            #pragma unroll
            for (int j = 0; j < KC; ++j) {
                float wn = 1.0f / (fabsf(x[j]) + 0.01f);
                wl[j] = wn;
                if (kbase + j < K_) loc = fmaf(wn, wn, loc);   // mask pad k
            }
            #pragma unroll
            for (int mm = 1; mm < 64; mm <<= 1) loc += __shfl_xor(loc, mm);
            if (lane == 0) rb[tid >> 6] = loc;
            __syncthreads();
            if (tid == 0) {
                float tot = 0.f;
                #pragma unroll
                for (int wq = 0; wq < NT/64; ++wq) tot += rb[wq];
                atomicAdd(ws + WS_WN, tot);
            }
            grid_barrier(wsu + WS_BARC, wsu + WS_BARG);
            if (tid == 0)
                sbcast = __hip_atomic_load(ws + WS_WN, __ATOMIC_RELAXED,
                                           __HIP_MEMORY_SCOPE_AGENT);
            __syncthreads();
            float scale = ((float)K_) * (LAM_ * Linv) / sqrtf(sbcast);
            #pragma unroll
            for (int j = 0; j < KC; ++j) wl[j] *= scale;
        }
    }

    // ---- outputs: code ----
    #pragma unroll
    for (int j = 0; j < KC; ++j) {
        int kg = kbase + j;
        if (kg < K_) out[n*KM_ + kg*M_ + m] = x[j];
    }
    // ---- reconst = D @ code (reuse phase-A machinery on final x) ----
    #pragma unroll 2
    for (int t = 0; t < T_; ++t) {
        const float4* dp = (const float4*)(Dl + t*PADK + kbase);
        float z0=0.f, z1=0.f, z2=0.f, z3=0.f;
        #pragma unroll
        for (int q = 0; q < KC/4; ++q) {
            float4 d = dp[q];
            z0 = fmaf(d.x, x[4*q+0], z0);
            z1 = fmaf(d.y, x[4*q+1], z1);
            z2 = fmaf(d.z, x[4*q+2], z2);
            z3 = fmaf(d.w, x[4*q+3], z3);
        }
        float z = (z0+z1) + (z2+z3);
        z += __shfl_xor(z, 1);
        z += __shfl_xor(z, 2);
        z += __shfl_xor(z, 4);
        if (kq == (t & 7)) out[OUT_REC + n*TM_ + t*M_ + m] = z;
    }
}

// ---------------------------------------------------------------------------
extern "C" void kernel_launch(void* const* d_in, const int* in_sizes, int n_in,
                              void* d_out, int out_size, void* d_ws, size_t ws_size,
                              hipStream_t stream) {
    const float* X  = (const float*)d_in[0];
    const float* rr = (const float*)d_in[1];
    const float* th = (const float*)d_in[2];
    float* out = (float*)d_out;
    float* ws  = (float*)d_ws;

    // zero conv accumulators + wn accumulator + barrier state (every call)
    hipMemsetAsync((char*)d_ws + WS_ACC*sizeof(float), 0, 4096, stream);
    k_dict<<<dim3(1), dim3(256), 0, stream>>>(rr, th, out, ws);
    k_fista<<<dim3(NB), dim3(NT), 0, stream>>>(X, out, ws);
}

// Round 2
// 1888.640 us; speedup vs baseline: 1.1969x; 1.1969x over previous
//
#include <hip/hip_runtime.h>
#include <math.h>

// ---------------- problem constants (fixed by setup_inputs) ----------------
#define N_    256
#define T_    36
#define M_    50
#define P_    80
#define K_    161          // 1 + 2P
#define PADK  192          // K padded to 8*24, pad cols are zero
#define KC    24           // k-elements per lane (8 lanes per column)
#define NB    200          // blocks (<= 256 CUs, all co-resident)
#define NT    256          // threads per block; 4 waves; 2 cols/thread
                           // 200*256/8*2 = 12800 columns
#define LAM_  0.1f
#define MAXIT 100

#define KM_     (K_*M_)        // 8050
#define TM_     (T_*M_)        // 1800
#define OUT_DIC 2060800        // N*K*M
#define OUT_REC 2066596        // + T*K

// ---- workspace float offsets ----
#define WS_LINV 0
#define WS_D    64             // 36*192 = 6912 floats
#define WS_ACC  8192           // 200 floats (per-iter global sum of dx^2)
#define WS_WN   8392           // 1 float  (sum of wn^2)
#define WS_BARC 8396           // unsigned: barrier count
#define WS_BARG 8397           // unsigned: barrier generation

// ---------------------------------------------------------------------------
// kernel 1: build dictionary (write dic output + padded D to ws) and
// Linv = 1/frob(DtD) using frob(DtD) == frob(D D^T)  (36x36 instead of 161^2)
// ---------------------------------------------------------------------------
__global__ __launch_bounds__(256) void k_dict(const float* __restrict__ rr,
                                              const float* __restrict__ th,
                                              float* __restrict__ out,
                                              float* __restrict__ ws) {
    __shared__ float Dl[T_*PADK];
    const int tid = threadIdx.x;
    for (int e = tid; e < T_*PADK; e += 256) {
        int t = e / PADK, k = e - (e / PADK) * PADK;
        float v = 0.f;
        if (k == 0) v = 1.f;
        else if (k <= P_)      { float r = rr[k-1];     float a = th[k-1]*(float)t;
                                 v = powf(r, (float)t) * cosf(a); }
        else if (k <= 2*P_)    { float r = rr[k-1-P_];  float a = th[k-1-P_]*(float)t;
                                 v = powf(r, (float)t) * sinf(a); }
        Dl[e] = v;
        ws[WS_D + e] = v;
        if (k < K_) out[OUT_DIC + t*K_ + k] = v;
    }
    __syncthreads();
    float loc = 0.f;
    for (int e = tid; e < T_*T_; e += 256) {
        int t1 = e / T_, t2 = e - (e / T_) * T_;
        float s = 0.f;
        for (int k = 0; k < K_; ++k) s = fmaf(Dl[t1*PADK+k], Dl[t2*PADK+k], s);
        loc = fmaf(s, s, loc);
    }
    #pragma unroll
    for (int mm = 1; mm < 64; mm <<= 1) loc += __shfl_xor(loc, mm);
    __shared__ float rb[4];
    if ((tid & 63) == 0) rb[tid >> 6] = loc;
    __syncthreads();
    if (tid == 0) {
        float tot = rb[0] + rb[1] + rb[2] + rb[3];
        ws[WS_LINV] = 1.0f / sqrtf(tot);
    }
}

// ---------------------------------------------------------------------------
// handmade grid barrier (generation-based; all NB blocks are co-resident)
// ---------------------------------------------------------------------------
__device__ __forceinline__ void grid_barrier(unsigned* cnt, unsigned* gen) {
    __syncthreads();
    if (threadIdx.x == 0) {
        __threadfence();
        unsigned g0 = __hip_atomic_load(gen, __ATOMIC_ACQUIRE, __HIP_MEMORY_SCOPE_AGENT);
        unsigned my = __hip_atomic_fetch_add(cnt, 1u, __ATOMIC_ACQ_REL, __HIP_MEMORY_SCOPE_AGENT);
        if (my == NB - 1u) {
            __hip_atomic_store(cnt, 0u, __ATOMIC_RELAXED, __HIP_MEMORY_SCOPE_AGENT);
            __hip_atomic_fetch_add(gen, 1u, __ATOMIC_RELEASE, __HIP_MEMORY_SCOPE_AGENT);
        } else {
            while (__hip_atomic_load(gen, __ATOMIC_ACQUIRE, __HIP_MEMORY_SCOPE_AGENT) == g0)
                __builtin_amdgcn_s_sleep(1);
        }
        __threadfence();
    }
    __syncthreads();
}

// ---- DPP-based 8-lane sum (pure VALU, off the LDS pipe) --------------------
// After xor1+xor2 every lane of a quad holds the quad sum, so row_half_mirror
// (i -> i^7 within each 8-group) delivers the other quad's sum: bit-identical
// to the xor1/xor2/xor4 shuffle butterfly.
template<int CTRL>
__device__ __forceinline__ float dpp_mov(float v) {
    int p = __builtin_amdgcn_update_dpp(0, __float_as_int(v), CTRL, 0xF, 0xF, true);
    return __int_as_float(p);
}
__device__ __forceinline__ float reduce8(float z) {
    z += dpp_mov<0xB1>(z);    // quad_perm [1,0,3,2]  (xor 1)
    z += dpp_mov<0x4E>(z);    // quad_perm [2,3,0,1]  (xor 2)
    z += dpp_mov<0x141>(z);   // row_half_mirror      (other quad)
    return z;
}

// ---------------------------------------------------------------------------
// kernel 2: persistent FISTA. Each column (n,m) is split across 8 lanes
// (kq = lane&7, 24 k's each, zero-padded). 2 columns per thread amortize the
// LDS D-tile reads (6 ds_read_b128 per t feed 96 FMAs). State in registers.
// ---------------------------------------------------------------------------
__global__ __launch_bounds__(NT, 1) void k_fista(const float* __restrict__ X,
                                                 float* __restrict__ out,
                                                 float* __restrict__ ws) {
    __shared__ __align__(16) float Dl[T_*PADK];
    __shared__ int   sniter;
    __shared__ float sbcast;

    unsigned* wsu = (unsigned*)ws;
    const int tid = threadIdx.x;

    for (int e = tid; e < T_*PADK; e += NT) Dl[e] = ws[WS_D + e];
    const float Linv = ws[WS_LINV];
    __syncthreads();

    const int lane  = tid & 63;
    const int kq    = lane & 7;
    const int gw    = (int)blockIdx.x * (NT/64) + (tid >> 6);
    const int colb  = gw*16 + (lane >> 3)*2;       // [0, 12800), 2 cols/thread
    const int n0    = colb / M_;
    const int m0    = colb - n0*M_;
    const int n1    = (colb+1) / M_;
    const int m1    = (colb+1) - n1*M_;
    const int kbase = kq * KC;                     // kq=7 -> all-zero pad region
    const float* Y0 = X + n0*TM_ + m0;
    const float* Y1 = X + n1*TM_ + m1;

    float x[2][KC], y[2][KC], b[2][KC], wl[2][KC];

    // ---- b = Linv * (D^T Ycol) for both columns ----
    #pragma unroll
    for (int j = 0; j < KC; ++j) { b[0][j] = 0.f; b[1][j] = 0.f; }
    #pragma unroll 2
    for (int t = 0; t < T_; ++t) {
        float yv0 = Y0[t*M_], yv1 = Y1[t*M_];
        const float4* dp = (const float4*)(Dl + t*PADK + kbase);
        #pragma unroll
        for (int q = 0; q < KC/4; ++q) {
            float4 d = dp[q];
            b[0][4*q+0] = fmaf(d.x, yv0, b[0][4*q+0]);
            b[0][4*q+1] = fmaf(d.y, yv0, b[0][4*q+1]);
            b[0][4*q+2] = fmaf(d.z, yv0, b[0][4*q+2]);
            b[0][4*q+3] = fmaf(d.w, yv0, b[0][4*q+3]);
            b[1][4*q+0] = fmaf(d.x, yv1, b[1][4*q+0]);
            b[1][4*q+1] = fmaf(d.y, yv1, b[1][4*q+1]);
            b[1][4*q+2] = fmaf(d.z, yv1, b[1][4*q+2]);
            b[1][4*q+3] = fmaf(d.w, yv1, b[1][4*q+3]);
        }
    }
    #pragma unroll
    for (int j = 0; j < KC; ++j) { b[0][j] *= Linv; b[1][j] *= Linv; }

    // pass-1 weights: w = 1 -> wl = lam*Linv
    #pragma unroll
    for (int j = 0; j < KC; ++j) { wl[0][j] = LAM_ * Linv; wl[1][j] = LAM_ * Linv; }

    float tcur = 1.f;

    // one FISTA iteration for both columns; returns this thread's sum of dx^2
    auto iterate = [&]() -> float {
        float u[2][KC];
        #pragma unroll
        for (int j = 0; j < KC; ++j) { u[0][j] = 0.f; u[1][j] = 0.f; }
        #pragma unroll 2
        for (int t = 0; t < T_; ++t) {
            const float4* dp = (const float4*)(Dl + t*PADK + kbase);
            float4 da[KC/4];
            #pragma unroll
            for (int q = 0; q < KC/4; ++q) da[q] = dp[q];
            float z00=0.f, z01=0.f, z02=0.f, z03=0.f;
            float z10=0.f, z11=0.f, z12=0.f, z13=0.f;
            #pragma unroll
            for (int q = 0; q < KC/4; ++q) {
                z00 = fmaf(da[q].x, y[0][4*q+0], z00);
                z01 = fmaf(da[q].y, y[0][4*q+1], z01);
                z02 = fmaf(da[q].z, y[0][4*q+2], z02);
                z03 = fmaf(da[q].w, y[0][4*q+3], z03);
                z10 = fmaf(da[q].x, y[1][4*q+0], z10);
                z11 = fmaf(da[q].y, y[1][4*q+1], z11);
                z12 = fmaf(da[q].z, y[1][4*q+2], z12);
                z13 = fmaf(da[q].w, y[1][4*q+3], z13);
            }
            float z0 = (z00+z01) + (z02+z03);
            float z1 = (z10+z11) + (z12+z13);
            z0 = reduce8(z0);                      // all 8 lanes hold z_t (col 0)
            z1 = reduce8(z1);
            #pragma unroll
            for (int q = 0; q < KC/4; ++q) {
                u[0][4*q+0] = fmaf(da[q].x, z0, u[0][4*q+0]);
                u[0][4*q+1] = fmaf(da[q].y, z0, u[0][4*q+1]);
                u[0][4*q+2] = fmaf(da[q].z, z0, u[0][4*q+2]);
                u[0][4*q+3] = fmaf(da[q].w, z0, u[0][4*q+3]);
                u[1][4*q+0] = fmaf(da[q].x, z1, u[1][4*q+0]);
                u[1][4*q+1] = fmaf(da[q].y, z1, u[1][4*q+1]);
                u[1][4*q+2] = fmaf(da[q].z, z1, u[1][4*q+2]);
                u[1][4*q+3] = fmaf(da[q].w, z1, u[1][4*q+3]);
            }
        }
        float t0 = tcur;
        float t1 = 0.5f * (1.f + sqrtf(fmaf(4.f*t0, t0, 1.f)));
        float tt = (t0 - 1.f) / t1;
        tcur = t1;
        float ss = 0.f;
        #pragma unroll
        for (int c = 0; c < 2; ++c) {
            #pragma unroll
            for (int j = 0; j < KC; ++j) {
                float Ay = fmaf(-Linv, u[c][j], y[c][j]);  // y - Linv*D^T(D y)
                float s  = Ay + b[c][j];
                float xn = fmaxf(0.f, s - wl[c][j]) + fminf(0.f, s + wl[c][j]);
                float d  = xn - x[c][j];
                ss    = fmaf(d, d, ss);
                y[c][j] = fmaf(tt, d, xn);
                x[c][j] = xn;
            }
        }
        return ss;
    };

    auto run = [&](int nit, bool record, int accbase) {
        tcur = 1.f;
        #pragma unroll
        for (int j = 0; j < KC; ++j) {
            x[0][j] = 0.f; x[1][j] = 0.f; y[0][j] = 0.f; y[1][j] = 0.f;
        }
        for (int i = 0; i < nit; ++i) {
            float ss = iterate();
            if (record) {
                #pragma unroll
                for (int mm = 1; mm < 64; mm <<= 1) ss += __shfl_xor(ss, mm);
                if (lane == 0) atomicAdd(ws + WS_ACC + accbase + i, ss);
            }
        }
    };

    const float THR2 = (1e-5f * (float)K_) * (1e-5f * (float)K_);  // (tol*K)^2

    #pragma unroll 1
    for (int pass = 0; pass < 2; ++pass) {
        // run 1: full 100 iters, record per-iter ||dx||^2 (fire-and-forget)
        run(MAXIT, true, pass*MAXIT);
        grid_barrier(wsu + WS_BARC, wsu + WS_BARG);

        // find c = first iter with conv; needed iters = c+1 (101 = never)
        if (tid == 0) sniter = MAXIT + 1;
        __syncthreads();
        if (tid < MAXIT) {
            float a = __hip_atomic_load(ws + WS_ACC + pass*MAXIT + tid,
                                        __ATOMIC_RELAXED, __HIP_MEMORY_SCOPE_AGENT);
            if (a < THR2) atomicMin(&sniter, tid + 1);
        }
        __syncthreads();
        int nit2 = sniter;                 // uniform across the whole grid
        if (nit2 < MAXIT) run(nit2, false, 0);   // deterministic replay to x_{c+1}

        if (pass == 0) {
            // reweight: wn = 1/(|code|+0.01); w = wn/||wn||*K; wl = w*lam*Linv
            float loc = 0.f;
            #pragma unroll
            for (int c = 0; c < 2; ++c) {
                #pragma unroll
                for (int j = 0; j < KC; ++j) {
                    float wn = 1.0f / (fabsf(x[c][j]) + 0.01f);
                    wl[c][j] = wn;
                    if (kbase + j < K_) loc = fmaf(wn, wn, loc);   // mask pad k
                }
            }
            #pragma unroll
            for (int mm = 1; mm < 64; mm <<= 1) loc += __shfl_xor(loc, mm);
            if (lane == 0) atomicAdd(ws + WS_WN, loc);
            grid_barrier(wsu + WS_BARC, wsu + WS_BARG);
            if (tid == 0)
                sbcast = __hip_atomic_load(ws + WS_WN, __ATOMIC_RELAXED,
                                           __HIP_MEMORY_SCOPE_AGENT);
            __syncthreads();
            float scale = ((float)K_) * (LAM_ * Linv) / sqrtf(sbcast);
            #pragma unroll
            for (int j = 0; j < KC; ++j) { wl[0][j] *= scale; wl[1][j] *= scale; }
        }
    }

    // ---- outputs: code ----
    #pragma unroll
    for (int j = 0; j < KC; ++j) {
        int kg = kbase + j;
        if (kg < K_) {
            out[n0*KM_ + kg*M_ + m0] = x[0][j];
            out[n1*KM_ + kg*M_ + m1] = x[1][j];
        }
    }
    // ---- reconst = D @ code (on final x, both columns) ----
    #pragma unroll 2
    for (int t = 0; t < T_; ++t) {
        const float4* dp = (const float4*)(Dl + t*PADK + kbase);
        float z00=0.f, z01=0.f, z02=0.f, z03=0.f;
        float z10=0.f, z11=0.f, z12=0.f, z13=0.f;
        #pragma unroll
        for (int q = 0; q < KC/4; ++q) {
            float4 d = dp[q];
            z00 = fmaf(d.x, x[0][4*q+0], z00);
            z01 = fmaf(d.y, x[0][4*q+1], z01);
            z02 = fmaf(d.z, x[0][4*q+2], z02);
            z03 = fmaf(d.w, x[0][4*q+3], z03);
            z10 = fmaf(d.x, x[1][4*q+0], z10);
            z11 = fmaf(d.y, x[1][4*q+1], z11);
            z12 = fmaf(d.z, x[1][4*q+2], z12);
            z13 = fmaf(d.w, x[1][4*q+3], z13);
        }
        float z0 = (z00+z01) + (z02+z03);
        float z1 = (z10+z11) + (z12+z13);
        z0 = reduce8(z0);
        z1 = reduce8(z1);
        if (kq == (t & 7)) {
            out[OUT_REC + n0*TM_ + t*M_ + m0] = z0;
            out[OUT_REC + n1*TM_ + t*M_ + m1] = z1;
        }
    }
}

// ---------------------------------------------------------------------------
extern "C" void kernel_launch(void* const* d_in, const int* in_sizes, int n_in,
                              void* d_out, int out_size, void* d_ws, size_t ws_size,
                              hipStream_t stream) {
    const float* X  = (const float*)d_in[0];
    const float* rr = (const float*)d_in[1];
    const float* th = (const float*)d_in[2];
    float* out = (float*)d_out;
    float* ws  = (float*)d_ws;

    // zero conv accumulators + wn accumulator + barrier state (every call)
    hipMemsetAsync((char*)d_ws + WS_ACC*sizeof(float), 0, 4096, stream);
    k_dict<<<dim3(1), dim3(256), 0, stream>>>(rr, th, out, ws);
    k_fista<<<dim3(NB), dim3(NT), 0, stream>>>(X, out, ws);
}